// Round 1
// 105.214 us; speedup vs baseline: 1.1290x; 1.1290x over previous
//
#include <hip/hip_runtime.h>

#define LSEQ   1024
#define NHEAD  8
#define DH     64
#define DIM    512
#define DF     192   // concatenated feature dim: [plain, cos, sin]
#define LDB    72    // ushort LDS row stride for proj tiles (144 B, 16B-aligned)
#define LDQ    200   // ushort LDS row stride for K' tiles (400 B)
#define LDV    72    // ushort LDS row stride for 64-wide tiles (144 B)

typedef __attribute__((ext_vector_type(8))) short short8;
typedef __attribute__((ext_vector_type(4))) float floatx4;

__device__ __forceinline__ unsigned short bf16_rne(float x) {
    unsigned int u = __float_as_uint(x);
    u += 0x7FFFu + ((u >> 16) & 1u);
    return (unsigned short)(u >> 16);
}
// packed f32x2 -> bf16x2 (RNE), single VALU op
__device__ __forceinline__ unsigned int pk_bf16(float lo, float hi) {
    unsigned int d;
    asm("v_cvt_pk_bf16_f32 %0, %1, %2" : "=v"(d) : "v"(lo), "v"(hi));
    return d;
}
__device__ __forceinline__ float softplus_fast(float x) {
    return (x > 15.f) ? x : __logf(1.f + __expf(x));
}

// ---------------------------------------------------------------------------
// Kernel A: projections + feature map.  C = X @ W^T (bf16 MFMA, 64x64 tile).
// sel 0: q -> Q' = [softplus(q), q'*cos(l*w+bias), q'*sin(l*w+bias)]  (192-d)
// sel 1: k -> K' = [softplus(k), k'*cos(l*w),      k'*sin(l*w)]       (192-d)
// sel 2: v -> raw bf16, stored TRANSPOSED: vbuf[nh][e][l]  (for attn staging)
// ---------------------------------------------------------------------------
__global__ __launch_bounds__(256) void proj_kernel(
    const float* __restrict__ query, const float* __restrict__ key,
    const float* __restrict__ Wq, const float* __restrict__ Wk,
    const float* __restrict__ Wv,
    const float* __restrict__ pw, const float* __restrict__ pb,
    unsigned short* __restrict__ qf, unsigned short* __restrict__ kf,
    unsigned short* __restrict__ vbuf)
{
    const int mt  = blockIdx.x;
    const int ot  = blockIdx.y;
    const int sel = blockIdx.z;
    const int t   = threadIdx.x;

    const float* __restrict__ X = (sel == 0) ? query : key;
    const float* __restrict__ W = (sel == 0) ? Wq : (sel == 1) ? Wk : Wv;

    __shared__ unsigned short As[64 * LDB];
    __shared__ unsigned short Bs[64 * LDB];

    const int m0 = mt * 64, o0 = ot * 64;
    const int lane = t & 63, wave = t >> 6;
    const int quad = lane >> 4, l16 = lane & 15;
    const int wm = wave >> 1, wn = wave & 1;

    const int srow = t >> 2;
    const int sc16 = (t & 3) * 16;

    floatx4 acc[2][2];
    #pragma unroll
    for (int i = 0; i < 2; ++i)
        #pragma unroll
        for (int j = 0; j < 2; ++j) acc[i][j] = (floatx4){0.f, 0.f, 0.f, 0.f};

    float4 ax[4], bx4[4];
    #pragma unroll
    for (int i = 0; i < 4; ++i) {
        ax[i]  = *(const float4*)&X[(size_t)(m0 + srow) * DIM + sc16 + i * 4];
        bx4[i] = *(const float4*)&W[(size_t)(o0 + srow) * DIM + sc16 + i * 4];
    }

    for (int kt = 0; kt < DIM; kt += 64) {
        __syncthreads();
        {
            unsigned int ua[8], ub[8];
            #pragma unroll
            for (int i = 0; i < 4; ++i) {
                ua[2*i]   = pk_bf16(ax[i].x, ax[i].y);
                ua[2*i+1] = pk_bf16(ax[i].z, ax[i].w);
                ub[2*i]   = pk_bf16(bx4[i].x, bx4[i].y);
                ub[2*i+1] = pk_bf16(bx4[i].z, bx4[i].w);
            }
            *(uint4*)&As[srow * LDB + sc16]     = *(uint4*)&ua[0];
            *(uint4*)&As[srow * LDB + sc16 + 8] = *(uint4*)&ua[4];
            *(uint4*)&Bs[srow * LDB + sc16]     = *(uint4*)&ub[0];
            *(uint4*)&Bs[srow * LDB + sc16 + 8] = *(uint4*)&ub[4];
        }
        __syncthreads();

        if (kt + 64 < DIM) {
            #pragma unroll
            for (int i = 0; i < 4; ++i) {
                ax[i]  = *(const float4*)&X[(size_t)(m0 + srow) * DIM + kt + 64 + sc16 + i * 4];
                bx4[i] = *(const float4*)&W[(size_t)(o0 + srow) * DIM + kt + 64 + sc16 + i * 4];
            }
        }

        #pragma unroll
        for (int s = 0; s < 2; ++s) {
            short8 af[2], bf[2];
            #pragma unroll
            for (int mi = 0; mi < 2; ++mi)
                af[mi] = *(const short8*)&As[(wm * 32 + mi * 16 + l16) * LDB + s * 32 + quad * 8];
            #pragma unroll
            for (int ni = 0; ni < 2; ++ni)
                bf[ni] = *(const short8*)&Bs[(wn * 32 + ni * 16 + l16) * LDB + s * 32 + quad * 8];
            #pragma unroll
            for (int ni = 0; ni < 2; ++ni)
                #pragma unroll
                for (int mi = 0; mi < 2; ++mi)
                    acc[mi][ni] = __builtin_amdgcn_mfma_f32_16x16x32_bf16(af[mi], bf[ni], acc[mi][ni], 0, 0, 0);
        }
    }

    const int h = ot;   // o0 = h*64
    const float PI_ = 3.14159265358979323846f;
    const int n_ = m0 >> 10;

    if (sel == 2) {
        // transpose 64x64 tile through LDS, write vbuf[nh][e][l] coalesced
        __syncthreads();
        #pragma unroll
        for (int mi = 0; mi < 2; ++mi)
            #pragma unroll
            for (int ni = 0; ni < 2; ++ni) {
                const int d = wn * 32 + ni * 16 + l16;
                #pragma unroll
                for (int r = 0; r < 4; ++r) {
                    const int ml = wm * 32 + mi * 16 + quad * 4 + r;
                    As[ml * LDB + d] = bf16_rne(acc[mi][ni][r]);
                }
            }
        __syncthreads();
        const int d = t >> 2, mq = (t & 3) * 16;
        const int l0 = m0 & (LSEQ - 1);
        unsigned short col[16];
        #pragma unroll
        for (int j = 0; j < 16; ++j) col[j] = As[(mq + j) * LDB + d];
        unsigned short* dst = &vbuf[((size_t)(n_ * NHEAD + h) * DH + d) * LSEQ + l0 + mq];
        *(short8*)&dst[0] = *(short8*)&col[0];
        *(short8*)&dst[8] = *(short8*)&col[8];
    } else {
        unsigned short* __restrict__ obuf = (sel == 0) ? qf : kf;
        #pragma unroll
        for (int ni = 0; ni < 2; ++ni) {
            const int d = wn * 32 + ni * 16 + l16;
            const float w = pw[h * DH + d];
            const float bias = (sel == 0) ? PI_ / (1.f + __expf(-pb[h * DH + d])) : 0.f;
            // sincos of the step and base; 16-step by angle doubling
            float s1, c1; sincosf(w, &s1, &c1);
            const float c2  = c1*c1 - s1*s1,  s2  = 2.f*c1*s1;
            const float c4  = c2*c2 - s2*s2,  s4  = 2.f*c2*s2;
            const float c8  = c4*c4 - s4*s4,  s8  = 2.f*c4*s4;
            const float c16 = c8*c8 - s8*s8,  s16 = 2.f*c8*s8;
            const int lb = (m0 & (LSEQ - 1)) + wm * 32 + quad * 4;
            float sb, cb; sincosf((float)lb * w + bias, &sb, &cb);
            #pragma unroll
            for (int mi = 0; mi < 2; ++mi) {
                float cc = cb, ss = sb;
                #pragma unroll
                for (int r = 0; r < 4; ++r) {
                    const int l = lb + mi * 16 + r;
                    const float val = softplus_fast(acc[mi][ni][r]);
                    const size_t ob = ((size_t)(n_ * NHEAD + h) * LSEQ + l) * DF + d;
                    obuf[ob]          = bf16_rne(val);
                    obuf[ob + DH]     = bf16_rne(val * cc);
                    obuf[ob + 2*DH]   = bf16_rne(val * ss);
                    const float nc = cc * c1 - ss * s1;   // rotate by w
                    ss = ss * c1 + cc * s1; cc = nc;
                }
                const float nb = cb * c16 - sb * s16;     // rotate base by 16w
                sb = sb * c16 + cb * s16; cb = nb;
            }
        }
    }
}

// ---------------------------------------------------------------------------
// Kernel B (flash-style quadratic attention over 192-d features):
//   S = tril(Q' K'^T);  out = (S V) / rowsum(S)
// Flat 512-block grid, decoded so that (empirical round-robin XCD = b%8):
//   - each XCD owns nh in {2x,2x+1}  -> qf/kf/v working set ~1.8 MB fits L2
//   - blocks b and b+256 (light lt=p / heavy lt=31-p) share a CU -> 17 it/CU
// Q' held in registers; next K'/V tile prefetched to registers during MFMA
// and written to LDS after the post-GEMM2 barrier (async-stage split).
// ---------------------------------------------------------------------------
__global__ __launch_bounds__(256) void attn_kernel(
    const unsigned short* __restrict__ qf, const unsigned short* __restrict__ kf,
    const unsigned short* __restrict__ vbuf,
    float* __restrict__ outp)
{
    const int b  = blockIdx.x;
    const int nh = (b & 7) * 2 + ((b >> 3) & 1);
    const int p  = (b >> 4) & 15;
    const int z  = b >> 8;
    const int lt = z ? (31 - p) : p;
    const int n  = nh >> 3;
    const int h  = nh & (NHEAD - 1);
    const int t  = threadIdx.x;
    const int lane = t & 63, wave = t >> 6;
    const int quad = lane >> 4, l16 = lane & 15;
    const int wm = wave >> 1, wn = wave & 1;   // wave tile: 16 rows x 32 cols

    __shared__ unsigned short kL[64 * LDQ];   // K' tile [64][192]
    __shared__ unsigned short vT[64 * LDV];   // V^T tile [e][k]
    __shared__ unsigned short scA[32 * LDV];  // masked scores bf16 [l][k]
    __shared__ float denL[2][32];
    __shared__ float inv32[32];

    const size_t fbase = (size_t)nh * LSEQ;
    const int nkt = (lt >> 1) + 1;
    const int diag_kt = lt >> 1;

    // Q' fragments live in registers (per-lane clean global reads)
    short8 qreg[6];
    {
        const unsigned short* qrow = &qf[(fbase + lt * 32 + wm * 16 + l16) * DF + quad * 8];
        #pragma unroll
        for (int kk = 0; kk < 6; ++kk)
            qreg[kk] = *(const short8*)&qrow[kk * 32];
    }

    // K' staging geometry: 6 ushort8 chunks per thread (64 rows x 24 chunks)
    int kr[6], kc[6];
    #pragma unroll
    for (int c = 0; c < 6; ++c) {
        const int idx = c * 256 + t;
        kr[c] = idx / 24;
        kc[c] = (idx % 24) * 8;
    }
    const unsigned short* kfb = &kf[fbase * DF];
    // V staging: thread owns row e, 32 contiguous bytes
    const int ve = t >> 2, vk = (t & 3) * 16;
    const unsigned short* vfb = &vbuf[((size_t)nh * DH + ve) * LSEQ + vk];

    short8 kpre[6], vpre[2];
    // prologue: stage tile 0
    #pragma unroll
    for (int c = 0; c < 6; ++c)
        kpre[c] = *(const short8*)&kfb[(size_t)kr[c] * DF + kc[c]];
    vpre[0] = *(const short8*)&vfb[0];
    vpre[1] = *(const short8*)&vfb[8];
    #pragma unroll
    for (int c = 0; c < 6; ++c)
        *(short8*)&kL[kr[c] * LDQ + kc[c]] = kpre[c];
    *(short8*)&vT[ve * LDV + vk]     = vpre[0];
    *(short8*)&vT[ve * LDV + vk + 8] = vpre[1];
    __syncthreads();

    floatx4 accN[2];
    accN[0] = (floatx4){0.f, 0.f, 0.f, 0.f};
    accN[1] = (floatx4){0.f, 0.f, 0.f, 0.f};
    float den4[4] = {0.f, 0.f, 0.f, 0.f};

    for (int kt = 0; kt < nkt; ++kt) {
        // issue next tile's global loads; they retire during GEMM1+GEMM2
        const bool pf = (kt + 1 < nkt);
        if (pf) {
            const size_t koff = (size_t)(kt + 1) * 64 * DF;
            #pragma unroll
            for (int c = 0; c < 6; ++c)
                kpre[c] = *(const short8*)&kfb[koff + (size_t)kr[c] * DF + kc[c]];
            vpre[0] = *(const short8*)&vfb[(kt + 1) * 64];
            vpre[1] = *(const short8*)&vfb[(kt + 1) * 64 + 8];
        }

        // GEMM1: scores(32x64) = Q'(32x192) . K'^T, K=192 in 6 steps
        floatx4 accS[2];
        accS[0] = (floatx4){0.f, 0.f, 0.f, 0.f};
        accS[1] = (floatx4){0.f, 0.f, 0.f, 0.f};
        #pragma unroll
        for (int kk = 0; kk < 6; ++kk) {
            #pragma unroll
            for (int ni = 0; ni < 2; ++ni) {
                const short8 bfr = *(const short8*)&kL[(wn * 32 + ni * 16 + l16) * LDQ + kk * 32 + quad * 8];
                accS[ni] = __builtin_amdgcn_mfma_f32_16x16x32_bf16(qreg[kk], bfr, accS[ni], 0, 0, 0);
            }
        }

        // mask (diagonal tile only), accumulate den (f32), write scA bf16
        const bool diag = (kt == diag_kt);
        #pragma unroll
        for (int ni = 0; ni < 2; ++ni) {
            const int kcolL = wn * 32 + ni * 16 + l16;
            const int kcolG = kt * 64 + kcolL;
            #pragma unroll
            for (int r = 0; r < 4; ++r) {
                const int lrowL = wm * 16 + quad * 4 + r;
                float sval = accS[ni][r];
                if (diag && kcolG > lt * 32 + lrowL) sval = 0.f;
                den4[r] += sval;
                scA[lrowL * LDV + kcolL] = bf16_rne(sval);
            }
        }
        __syncthreads();   // scA ready; kL fully consumed by GEMM1

        // GEMM2: num += scA(32x64) . V(64x64), K=64 in 2 steps
        #pragma unroll
        for (int kk = 0; kk < 2; ++kk) {
            const short8 a = *(const short8*)&scA[(wm * 16 + l16) * LDV + kk * 32 + quad * 8];
            #pragma unroll
            for (int ni = 0; ni < 2; ++ni) {
                const short8 bfr = *(const short8*)&vT[(wn * 32 + ni * 16 + l16) * LDV + kk * 32 + quad * 8];
                accN[ni] = __builtin_amdgcn_mfma_f32_16x16x32_bf16(a, bfr, accN[ni], 0, 0, 0);
            }
        }
        __syncthreads();   // vT/scA consumed -> safe to overwrite

        if (pf) {
            #pragma unroll
            for (int c = 0; c < 6; ++c)
                *(short8*)&kL[kr[c] * LDQ + kc[c]] = kpre[c];
            *(short8*)&vT[ve * LDV + vk]     = vpre[0];
            *(short8*)&vT[ve * LDV + vk + 8] = vpre[1];
            __syncthreads();   // next tile staged
        }
    }

    // den: reduce den4 over the 16 l16-lanes of each quadrant, then across wn
    #pragma unroll
    for (int r = 0; r < 4; ++r) {
        float s = den4[r];
        s += __shfl_xor(s, 1);
        s += __shfl_xor(s, 2);
        s += __shfl_xor(s, 4);
        s += __shfl_xor(s, 8);
        if (l16 == 0) denL[wn][wm * 16 + quad * 4 + r] = s;
    }
    __syncthreads();
    if (t < 32) inv32[t] = 1.f / (denL[0][t] + denL[1][t]);
    __syncthreads();

    // out = num * (1/den)
    #pragma unroll
    for (int ni = 0; ni < 2; ++ni) {
        const int e = wn * 32 + ni * 16 + l16;
        #pragma unroll
        for (int r = 0; r < 4; ++r) {
            const int row = wm * 16 + quad * 4 + r;
            outp[((size_t)n * LSEQ + lt * 32 + row) * DIM + h * DH + e] =
                accN[ni][r] * inv32[row];
        }
    }
}

extern "C" void kernel_launch(void* const* d_in, const int* in_sizes, int n_in,
                              void* d_out, int out_size, void* d_ws, size_t ws_size,
                              hipStream_t stream) {
    const float* query = (const float*)d_in[0];
    const float* key   = (const float*)d_in[1];
    const float* Wq    = (const float*)d_in[2];
    const float* Wk    = (const float*)d_in[3];
    const float* Wv    = (const float*)d_in[4];
    const float* pw    = (const float*)d_in[5];
    const float* pb    = (const float*)d_in[6];

    unsigned short* U = (unsigned short*)d_ws;
    unsigned short* qf   = U;                 // 16*1024*192 = 3,145,728 u16
    unsigned short* kf   = U + 3145728;       // 3,145,728 u16
    unsigned short* vbuf = U + 6291456;       // [nh][e][l] 1,048,576 u16

    proj_kernel<<<dim3(32, 8, 3), 256, 0, stream>>>(
        query, key, Wq, Wk, Wv, pw, pb, qf, kf, vbuf);
    attn_kernel<<<dim3(512, 1, 1), 256, 0, stream>>>(
        qf, kf, vbuf, (float*)d_out);
}